// Round 17
// baseline (162.867 us; speedup 1.0000x reference)
//
#include <hip/hip_runtime.h>
#include <hip/hip_bf16.h>

// MLA attention with weight absorption. Inputs fp32, internal bf16 MFMA,
// output fp32. Key identity (rank-32 latent KV):
//   S  = Q K^T = (x W_q W_k^T) lat^T  ->  Qlat = x @ W_qk   [M, 512]
//   out = (P V) W_o = (P lat) (W_v W_o) -> Olat = P @ lat   [M, 512]
// so attention runs entirely in the 32-dim latent space; K = V = lat
// (1 MB total, L2-resident).
//
// Softmax is max-free (scores hard-bounded << fp32 exp2 range; max
// subtraction is a pure exponent shift). P-row sums come free from the
// matrix pipe via an all-ones A-fragment MFMA. No cross-lane reductions.
//
// Attention v16 = r9/r14 proven body with FOUR heads per block.
// Mechanism: r4->r6 (1->2 heads) was the only attn win (+6%); v15
// falsified barrier-amortization as its cause, leaving intra-wave ILP
// (independent per-head QK->softmax->P->PV chains fill the ~42% idle
// issue slots). 4 heads = 4 chains; K/V frag reads shared 4-ways.
// Grid 512: xcd=idx&7 pins one (batch, head-quad) per XCD (lat slice
// L2-resident); qb(j) = j<32 ? 63-j : j-32 makes each CU's two blocks
// sum to exactly 33 iters.
// Failed directions (do not revisit): dbuf (r5), lane-local P (r7),
// direct-L2 frags (r10/r12), split-K (r11), stride-68+reorder (r13),
// 128-key shared stage (r15).
//
// Launch graph (4 kernels):
//   1. prep (merged): convert x -> bf16; absorb W_qk (scaled log2e/8) ->
//      WcombT[0:512]; transpose W_kv -> WcombT[512:544]; zero [544:640];
//      absorb W_vo -> WvoT
//   2. gemm128 mode 5: [Qlat | lat(+latT scatter)] = x @ WcombT  (N=640)
//   3. latent flash attention (v16, 4 heads/block)
//   4. gemm128 mode 3: out = Olat @ WvoT -> d_out fp32 (K=512)

#define T_SEQ  4096
#define NHEAD  16
#define DHEAD  64
#define DMODEL 1024
#define LATENT 32
#define BATCH  2
#define M_ROWS (BATCH * T_SEQ)

typedef __attribute__((ext_vector_type(8))) short bf16x8;
typedef __attribute__((ext_vector_type(4))) float f32x4;

__device__ __forceinline__ short f2bf(float f) {
  __hip_bfloat16 h = __float2bfloat16(f);
  return __builtin_bit_cast(short, h);
}

// hardware v_exp_f32: computes 2^x (NOT e^x) — cdna4_isa.md §3
__device__ __forceinline__ float exp2_hw(float x) {
  return __builtin_amdgcn_exp2f(x);
}

// async global->LDS, 16B per lane. LDS dest = wave-uniform base + lane*16.
__device__ __forceinline__ void gld_lds16(const short* g, short* l) {
  __builtin_amdgcn_global_load_lds(
      (const __attribute__((address_space(1))) void*)g,
      (__attribute__((address_space(3))) void*)l, 16, 0, 0);
}

// ------------------------------------------------- merged prep (weights + x)
// blocks    0- 63: absorb_qk -> WcombT rows 0-511 (scaled)
// blocks   64-127: absorb_vo -> WvoT
// blocks  128-255: transpose W_kv -> WcombT rows 512-543; zero rows 544-639
// blocks 256-8447: convert x -> bf16 (4 elems/thread)
__global__ __launch_bounds__(256)
void prep_weights(const float* __restrict__ Wq, const float* __restrict__ Wk,
                  const float* __restrict__ Wv, const float* __restrict__ Wo,
                  const float* __restrict__ Wkv, const float* __restrict__ x,
                  short* __restrict__ WcombT, short* __restrict__ WvoT,
                  short* __restrict__ xbf) {
  const int blk = blockIdx.x;
  const int tid = threadIdx.x;

  if (blk >= 256) {                    // ---- convert x -> bf16
    const int i = ((blk - 256) * 256 + tid) * 4;
    if (i < M_ROWS * DMODEL) {
      const f32x4 v = *(const f32x4*)(x + i);
      short4 o;
      o.x = f2bf(v[0]); o.y = f2bf(v[1]); o.z = f2bf(v[2]); o.w = f2bf(v[3]);
      *(short4*)(xbf + i) = o;
    }
    return;
  }

  if (blk < 64) {                      // ---- absorb_qk
    __shared__ float wk[32 * 64];
    const int h   = blk >> 2;
    const int dm0 = (blk & 3) * 256;
    {
      const int l  = tid >> 3;
      const int d0 = (tid & 7) * 8;
      *(f32x4*)(wk + l * 64 + d0)     = *(const f32x4*)(Wk + (size_t)l * DMODEL + h * 64 + d0);
      *(f32x4*)(wk + l * 64 + d0 + 4) = *(const f32x4*)(Wk + (size_t)l * DMODEL + h * 64 + d0 + 4);
    }
    __syncthreads();
    const int dm = dm0 + tid;
    float acc[32] = {};
    for (int dv = 0; dv < 16; ++dv) {
      const f32x4 wq = *(const f32x4*)(Wq + (size_t)dm * DMODEL + h * 64 + dv * 4);
#pragma unroll
      for (int jj = 0; jj < 4; ++jj)
#pragma unroll
        for (int l = 0; l < 32; ++l)
          acc[l] += wq[jj] * wk[l * 64 + dv * 4 + jj];
    }
    const float SCALE = 0.1803368801111f;   // (1/sqrt(64)) * log2(e)
#pragma unroll
    for (int l = 0; l < 32; ++l)
      WcombT[((size_t)(h * 32 + l)) * DMODEL + dm] = f2bf(acc[l] * SCALE);
  } else if (blk < 128) {              // ---- absorb_vo
    __shared__ float wvs[32 * 64];
    const int h  = (blk - 64) >> 2;
    const int n0 = ((blk - 64) & 3) * 256;
    {
      const int l  = tid >> 3;
      const int d0 = (tid & 7) * 8;
      *(f32x4*)(wvs + l * 64 + d0)     = *(const f32x4*)(Wv + (size_t)l * DMODEL + h * 64 + d0);
      *(f32x4*)(wvs + l * 64 + d0 + 4) = *(const f32x4*)(Wv + (size_t)l * DMODEL + h * 64 + d0 + 4);
    }
    __syncthreads();
    const int n = n0 + tid;
    float acc[32] = {};
    for (int d = 0; d < 64; ++d) {
      const float wo = Wo[(size_t)(h * 64 + d) * DMODEL + n];
#pragma unroll
      for (int l = 0; l < 32; ++l)
        acc[l] += wvs[l * 64 + d] * wo;
    }
#pragma unroll
    for (int l = 0; l < 32; ++l)
      WvoT[(size_t)n * 512 + h * 32 + l] = f2bf(acc[l]);
  } else {                             // ---- Wkv transpose + zero-fill
    const int i = (blk - 128) * 256 + tid;      // 0..32767
    const int k = i >> 5;
    const int l = i & 31;
    WcombT[(size_t)(512 + l) * DMODEL + k] = f2bf(Wkv[(size_t)k * LATENT + l]);
    // zero rows 544-639: 96*1024 = 98304 shorts = 3 per thread, exact
    short* z = WcombT + (size_t)544 * DMODEL + (size_t)i * 3;
    z[0] = 0; z[1] = 0; z[2] = 0;
  }
}

// ---------------------------------------------------------------- GEMM (big)
// m97 structure: 128x128 block tile, BK=32, 4 waves 2x2, global_load_lds w16,
// source-side XOR chunk swizzle. M%128==0, N%128==0, K%32==0.
// out_mode 3: fp32 row-major [M,N] -> Cf
// out_mode 5: cols<512 -> Qlat bf16 [M,512] (Cs); cols 512-543 -> lat bf16
//             [M,32] (Cs2) + latT [B,32,T] (Cs3); cols>=544 discarded.
__global__ __launch_bounds__(256)
void gemm128_kernel(const short* __restrict__ A, const short* __restrict__ Bt,
                    short* __restrict__ Cs, float* __restrict__ Cf,
                    short* __restrict__ Cs2, short* __restrict__ Cs3,
                    int M, int K, int N, int out_mode) {
  __shared__ short Alds[128 * 32];   // 8 KB
  __shared__ short Blds[128 * 32];   // 8 KB

  const int tid  = threadIdx.x;
  const int wv   = tid >> 6;
  const int lane = tid & 63;
  const int quad = lane >> 4;
  const int l16  = lane & 15;
  const int wm   = wv >> 1;
  const int wn   = wv & 1;

  const int nb  = N >> 7;
  const int nwg = gridDim.x;
  int bid = blockIdx.x;
  if ((nwg & 7) == 0)                // XCD swizzle (bijective: nwg%8==0)
    bid = (bid & 7) * (nwg >> 3) + (bid >> 3);
  const int mt = bid / nb;
  const int nt = bid - mt * nb;
  const int m0 = mt << 7;
  const int n0 = nt << 7;

  const int rl  = lane >> 2;
  const int cl  = lane & 3;
  const int csw = cl ^ ((rl >> 1) & 3);
  const int ra  = wv * 16 + rl;
  const short* Ag0 = A  + (size_t)(m0 + ra) * K + csw * 8;
  const short* Ag1 = A  + (size_t)(m0 + 64 + ra) * K + csw * 8;
  const short* Bg0 = Bt + (size_t)(n0 + ra) * K + csw * 8;
  const short* Bg1 = Bt + (size_t)(n0 + 64 + ra) * K + csw * 8;
  short* Al0 = &Alds[(wv * 16) * 32];
  short* Al1 = &Alds[(64 + wv * 16) * 32];
  short* Bl0 = &Blds[(wv * 16) * 32];
  short* Bl1 = &Blds[(64 + wv * 16) * 32];

  const int rsw = (l16 >> 1) & 3;
  const int coff = (quad ^ rsw) * 8;

  f32x4 acc[4][4] = {};

  for (int k0 = 0; k0 < K; k0 += 32) {
    gld_lds16(Ag0 + k0, Al0);
    gld_lds16(Ag1 + k0, Al1);
    gld_lds16(Bg0 + k0, Bl0);
    gld_lds16(Bg1 + k0, Bl1);
    __builtin_amdgcn_s_waitcnt(0x0F70);   // vmcnt(0)
    __syncthreads();

    bf16x8 af[4], bfr[4];
#pragma unroll
    for (int i = 0; i < 4; ++i) {
      const int rowA = wm * 64 + i * 16 + l16;
      const int rowB = wn * 64 + i * 16 + l16;
      af[i]  = *(const bf16x8*)&Alds[rowA * 32 + coff];
      bfr[i] = *(const bf16x8*)&Blds[rowB * 32 + coff];
    }
#pragma unroll
    for (int i = 0; i < 4; ++i)
#pragma unroll
      for (int j = 0; j < 4; ++j)
        acc[i][j] = __builtin_amdgcn_mfma_f32_16x16x32_bf16(af[i], bfr[j], acc[i][j], 0, 0, 0);
    __syncthreads();
  }

  // epilogue: C/D layout row = quad*4+r (A side), col = l16 (B side)
#pragma unroll
  for (int i = 0; i < 4; ++i) {
    const int row = m0 + wm * 64 + i * 16 + quad * 4;
#pragma unroll
    for (int j = 0; j < 4; ++j) {
      const int col = n0 + wn * 64 + j * 16 + l16;
#pragma unroll
      for (int r = 0; r < 4; ++r) {
        if (out_mode == 3) {
          Cf[(size_t)(row + r) * N + col] = acc[i][j][r];
        } else {   // mode 5
          if (col < 512) {
            Cs[(size_t)(row + r) * 512 + col] = f2bf(acc[i][j][r]);
          } else if (col < 544) {
            const short v = f2bf(acc[i][j][r]);
            const int l = col - 512;
            const int m = row + r;
            Cs2[(size_t)m * LATENT + l] = v;
            const int bb = m >> 12;            // T_SEQ = 4096
            const int tt = m & (T_SEQ - 1);
            Cs3[((size_t)(bb * LATENT + l) << 12) + tt] = v;
          }
        }
      }
    }
  }
}

// ---------------------------------------------------------------- attention
// v16: r9 proven body, FOUR heads per block (intra-wave ILP: 4 independent
// QK->softmax->P->PV chains; K/V frag reads shared 4-ways).
// Block = 4 waves = 64 queries. Per 64-key tile: stage lat [64x32] + latT
// [32x64] (8 KB, single-buffered). Per wave per head: S^T = lat Qlat^T
// (4 MFMA), P = exp2(S^T), P roundtrip via wave-private LDS,
// Olat^T += latT P^T (4 MFMA), l += ones P^T (2 MFMA).
// Grid 512: xcd=idx&7 -> (batch, head-quad); qb = j<32 ? 63-j : j-32
// (each CU's two blocks sum to exactly 33 iters).
__global__ __launch_bounds__(256, 2)
void attn_kernel(const short* __restrict__ Qlat, short* __restrict__ Olat,
                 const short* __restrict__ latg, const short* __restrict__ latTg) {
  __shared__ short Klds[64 * 32];        // lat  [key][lat chunk swz]   4 KB
  __shared__ short Vlds[32 * 64];        // latT [lat][key chunk swz]   4 KB
  __shared__ short Plds[4][4][16 * 72];  // per-wave P, 4 heads        36.9 KB

  const int tid  = threadIdx.x;
  const int wv   = tid >> 6;
  const int lane = tid & 63;
  const int quad = lane >> 4;
  const int l16  = lane & 15;

  const int idx = blockIdx.x;             // 512 blocks
  const int xcd = idx & 7;                // (batch, head-quad) pinned per XCD
  const int j   = idx >> 3;               // 0..63
  const int qb  = (j < 32) ? (63 - j) : (j - 32);   // CU pairs sum to 33 iters
  const int b   = xcd >> 2;
  const int hq  = xcd & 3;                // heads hq*4 .. hq*4+3

  const int q0 = qb * 64;
  const int qw = q0 + wv * 16;            // this wave's query base
  const int q  = qw + l16;                // this lane's query (column)

  // staging geometry (per wave, 1 instr per tile), source-side XOR swizzle
  const int srK = wv * 16 + (lane >> 2);           // lat tile row (0..63)
  const int scK = (lane & 3) ^ ((srK >> 1) & 3);   // chunk of 16B in 64B row
  const short* Ksrc = latg + ((size_t)b * T_SEQ + srK) * LATENT + scK * 8;
  const int srV = wv * 8 + (lane >> 3);            // latT tile row (0..31)
  const int scV = (lane & 7) ^ (srV & 7);          // chunk of 16B in 128B row
  const short* Vsrc = latTg + ((size_t)b * LATENT + srV) * T_SEQ + scV * 8;

  // Qlat B-fragments for all four heads (cols hq*128 + c*32 .. +31)
  const short* Qrow = Qlat + ((size_t)(b * T_SEQ) + qw + l16) * 512 + hq * 128;
  bf16x8 qf[4];
#pragma unroll
  for (int c = 0; c < 4; ++c)
    qf[c] = *(const bf16x8*)(Qrow + c * 32 + quad * 8);

  // all-ones A-fragment: row-sum of P via the matrix pipe
  bf16x8 ones;
#pragma unroll
  for (int i = 0; i < 8; ++i) ones[i] = (short)0x3F80;   // bf16 1.0

  f32x4 o[4][2] = {};
  f32x4 lacc[4] = {};

  auto kv_step = [&](const int k0, const bool diag) {
    gld_lds16(Ksrc + (size_t)k0 * LATENT, &Klds[(wv * 16) * 32]);
    gld_lds16(Vsrc + k0,                  &Vlds[(wv * 8) * 64]);
    __builtin_amdgcn_s_waitcnt(0x0F70);   // vmcnt(0)
    __syncthreads();

    // ---- S^T = lat Qlat^T for FOUR heads (shared K A-frag)
    f32x4 s[4][4];
    __builtin_amdgcn_s_setprio(1);
#pragma unroll
    for (int mt = 0; mt < 4; ++mt) {
      if (diag && mt > wv) {               // keys entirely above all queries
#pragma unroll
        for (int c = 0; c < 4; ++c)
          s[c][mt][0] = s[c][mt][1] = s[c][mt][2] = s[c][mt][3] = -1e9f;
        continue;
      }
      const int R = mt * 16 + l16;
      const bf16x8 kf = *(const bf16x8*)&Klds[R * 32 + ((quad ^ ((R >> 1) & 3))) * 8];
      f32x4 z = {};
#pragma unroll
      for (int c = 0; c < 4; ++c)
        s[c][mt] = __builtin_amdgcn_mfma_f32_16x16x32_bf16(kf, qf[c], z, 0, 0, 0);
    }
    __builtin_amdgcn_s_setprio(0);

    // ---- causal mask: only the diagonal block needs it
    if (diag) {
#pragma unroll
      for (int mt = 0; mt < 4; ++mt)
#pragma unroll
        for (int r = 0; r < 4; ++r) {
          const int key = k0 + mt * 16 + quad * 4 + r;
          if (key > q) {
#pragma unroll
            for (int c = 0; c < 4; ++c) s[c][mt][r] = -1e9f;
          }
        }
    }

    // ---- P = exp2(S): max-free
#pragma unroll
    for (int c = 0; c < 4; ++c)
#pragma unroll
      for (int mt = 0; mt < 4; ++mt)
#pragma unroll
        for (int r = 0; r < 4; ++r)
          s[c][mt][r] = exp2_hw(s[c][mt][r]);

    // ---- P -> wave-private LDS (4 heads), read back as B-frags
    asm volatile("" ::: "memory");
#pragma unroll
    for (int c = 0; c < 4; ++c)
#pragma unroll
      for (int mt = 0; mt < 4; ++mt) {
        short4 w;
        w.x = f2bf(s[c][mt][0]); w.y = f2bf(s[c][mt][1]);
        w.z = f2bf(s[c][mt][2]); w.w = f2bf(s[c][mt][3]);
        *(short4*)(&Plds[wv][c][0] + l16 * 72 + mt * 16 + quad * 4) = w;
      }
    asm volatile("" ::: "memory");
    __builtin_amdgcn_s_waitcnt(0xC07F);   // lgkmcnt(0)
    asm volatile("" ::: "memory");
    bf16x8 pf[4][2];
#pragma unroll
    for (int c = 0; c < 4; ++c) {
      pf[c][0] = *(const bf16x8*)(&Plds[wv][c][0] + l16 * 72 + quad * 8);
      pf[c][1] = *(const bf16x8*)(&Plds[wv][c][0] + l16 * 72 + 32 + quad * 8);
    }
    asm volatile("" ::: "memory");

    // ---- Olat^T += latT P^T; l += ones P^T (4 heads, shared V A-frags)
    __builtin_amdgcn_s_setprio(1);
#pragma unroll
    for (int f = 0; f < 2; ++f) {
      const int R = f * 16 + l16;
      const bf16x8 vf0 = *(const bf16x8*)&Vlds[R * 64 + ((quad    ) ^ (R & 7)) * 8];
      const bf16x8 vf1 = *(const bf16x8*)&Vlds[R * 64 + ((quad + 4) ^ (R & 7)) * 8];
#pragma unroll
      for (int c = 0; c < 4; ++c) {
        o[c][f] = __builtin_amdgcn_mfma_f32_16x16x32_bf16(vf0, pf[c][0], o[c][f], 0, 0, 0);
        o[c][f] = __builtin_amdgcn_mfma_f32_16x16x32_bf16(vf1, pf[c][1], o[c][f], 0, 0, 0);
      }
    }
#pragma unroll
    for (int c = 0; c < 4; ++c) {
      lacc[c] = __builtin_amdgcn_mfma_f32_16x16x32_bf16(ones, pf[c][0], lacc[c], 0, 0, 0);
      lacc[c] = __builtin_amdgcn_mfma_f32_16x16x32_bf16(ones, pf[c][1], lacc[c], 0, 0, 0);
    }
    __builtin_amdgcn_s_setprio(0);
    __syncthreads();   // all waves done reading Klds/Vlds before restage
  };

#pragma unroll 1
  for (int k0 = 0; k0 < q0; k0 += 64) kv_step(k0, false);   // interior
  kv_step(q0, true);                                        // diagonal

  // ---- epilogue: Olat^T C-layout row = latent = f*16+quad*4+r, col = l16.
  short* Orow = Olat + ((size_t)(b * T_SEQ) + qw + l16) * 512 + hq * 128;
#pragma unroll
  for (int c = 0; c < 4; ++c) {
    const float inv = 1.0f / lacc[c][0];
#pragma unroll
    for (int f = 0; f < 2; ++f) {
      short4 w;
      w.x = f2bf(o[c][f][0] * inv); w.y = f2bf(o[c][f][1] * inv);
      w.z = f2bf(o[c][f][2] * inv); w.w = f2bf(o[c][f][3] * inv);
      *(short4*)(Orow + c * 32 + f * 16 + quad * 4) = w;
    }
  }
}

// ---------------------------------------------------------------- launch
extern "C" void kernel_launch(void* const* d_in, const int* in_sizes, int n_in,
                              void* d_out, int out_size, void* d_ws, size_t ws_size,
                              hipStream_t stream) {
  const float* x   = (const float*)d_in[0];   // [2,4096,1024]
  const float* Wkv = (const float*)d_in[1];   // [1024,32]
  const float* Wk  = (const float*)d_in[2];   // [32,1024]
  const float* Wv  = (const float*)d_in[3];   // [32,1024]
  const float* Wq  = (const float*)d_in[4];   // [1024,1024]
  const float* Wo  = (const float*)d_in[5];   // [1024,1024]

  char* p = (char*)d_ws;
  auto carve = [&](size_t n) {
    char* r = p;
    p += (n + 255) & ~(size_t)255;
    return r;
  };
  short* xbf    = (short*)carve((size_t)M_ROWS * DMODEL * 2);   // 16 MB
  short* Qlat   = (short*)carve((size_t)M_ROWS * 512 * 2);      //  8 MB
  short* Olat   = (short*)carve((size_t)M_ROWS * 512 * 2);      //  8 MB
  short* lat    = (short*)carve((size_t)M_ROWS * LATENT * 2);   // 512 KB
  short* latT   = (short*)carve((size_t)M_ROWS * LATENT * 2);   // 512 KB
  short* WcombT = (short*)carve((size_t)640 * DMODEL * 2);      // 1.25 MB
  short* WvoT   = (short*)carve((size_t)DMODEL * 512 * 2);      //  1 MB

  // merged prep: weights (blocks 0-255) + x conversion (blocks 256-8447)
  prep_weights<<<256 + M_ROWS * DMODEL / 4 / 256, 256, 0, stream>>>(
      Wq, Wk, Wv, Wo, Wkv, x, WcombT, WvoT, xbf);

  // [Qlat | lat + latT] = x @ WcombT  (N=640, cols>=544 discarded)
  gemm128_kernel<<<(M_ROWS / 128) * (640 / 128), 256, 0, stream>>>(
      xbf, WcombT, Qlat, nullptr, lat, latT, M_ROWS, DMODEL, 640, 5);

  attn_kernel<<<512, 256, 0, stream>>>(Qlat, Olat, lat, latT);

  // out = Olat @ W_vo  [M,1024] fp32
  gemm128_kernel<<<(M_ROWS / 128) * (DMODEL / 128), 256, 0, stream>>>(
      Olat, WvoT, nullptr, (float*)d_out, nullptr, nullptr, M_ROWS, 512, DMODEL, 3);
}

// Round 18
// 140.902 us; speedup vs baseline: 1.1559x; 1.1559x over previous
//
#include <hip/hip_runtime.h>
#include <hip/hip_bf16.h>

// MLA attention with weight absorption. Inputs fp32, internal bf16 MFMA,
// output fp32. Key identity (rank-32 latent KV):
//   S  = Q K^T = (x W_q W_k^T) lat^T  ->  Qlat = x @ W_qk   [M, 512]
//   out = (P V) W_o = (P lat) (W_v W_o) -> Olat = P @ lat   [M, 512]
// so attention runs entirely in the 32-dim latent space; K = V = lat
// (1 MB total, L2-resident).
//
// Softmax is max-free (scores hard-bounded << fp32 exp2 range; max
// subtraction is a pure exponent shift). P-row sums come free from the
// matrix pipe via an all-ones A-fragment MFMA. No cross-lane reductions.
//
// Attention = round-9 proven body (best measured: 72us attn / 141us total).
// Session evidence — heads/block curve peaks at 2 (1->77, 2->72, 4->94us:
// ILP gain < TLP loss at 4). Failed directions (measured, do not revisit):
// dbuf (r5), lane-local P (r7), direct-L2 frags (r10/r12), split-K (r11),
// stride-68+stage-reorder (r13), 128-key shared stage (r15), 4 heads (r16).
// Bank conflicts (6.39M) are ~48cy/iter = ~2%, immaterial.
//
// Launch graph (4 kernels):
//   1. prep (merged): convert x -> bf16; absorb W_qk (scaled log2e/8) ->
//      WcombT[0:512]; transpose W_kv -> WcombT[512:544]; zero [544:640];
//      absorb W_vo -> WvoT
//   2. gemm128 mode 5: [Qlat | lat(+latT scatter)] = x @ WcombT  (N=640)
//   3. latent flash attention (2 heads/block)
//   4. gemm128 mode 3: out = Olat @ WvoT -> d_out fp32 (K=512)

#define T_SEQ  4096
#define NHEAD  16
#define DHEAD  64
#define DMODEL 1024
#define LATENT 32
#define BATCH  2
#define M_ROWS (BATCH * T_SEQ)

typedef __attribute__((ext_vector_type(8))) short bf16x8;
typedef __attribute__((ext_vector_type(4))) float f32x4;

__device__ __forceinline__ short f2bf(float f) {
  __hip_bfloat16 h = __float2bfloat16(f);
  return __builtin_bit_cast(short, h);
}

// hardware v_exp_f32: computes 2^x (NOT e^x) — cdna4_isa.md §3
__device__ __forceinline__ float exp2_hw(float x) {
  return __builtin_amdgcn_exp2f(x);
}

// async global->LDS, 16B per lane. LDS dest = wave-uniform base + lane*16.
__device__ __forceinline__ void gld_lds16(const short* g, short* l) {
  __builtin_amdgcn_global_load_lds(
      (const __attribute__((address_space(1))) void*)g,
      (__attribute__((address_space(3))) void*)l, 16, 0, 0);
}

// ------------------------------------------------- merged prep (weights + x)
// blocks    0- 63: absorb_qk -> WcombT rows 0-511 (scaled)
// blocks   64-127: absorb_vo -> WvoT
// blocks  128-255: transpose W_kv -> WcombT rows 512-543; zero rows 544-639
// blocks 256-8447: convert x -> bf16 (4 elems/thread)
__global__ __launch_bounds__(256)
void prep_weights(const float* __restrict__ Wq, const float* __restrict__ Wk,
                  const float* __restrict__ Wv, const float* __restrict__ Wo,
                  const float* __restrict__ Wkv, const float* __restrict__ x,
                  short* __restrict__ WcombT, short* __restrict__ WvoT,
                  short* __restrict__ xbf) {
  const int blk = blockIdx.x;
  const int tid = threadIdx.x;

  if (blk >= 256) {                    // ---- convert x -> bf16
    const int i = ((blk - 256) * 256 + tid) * 4;
    if (i < M_ROWS * DMODEL) {
      const f32x4 v = *(const f32x4*)(x + i);
      short4 o;
      o.x = f2bf(v[0]); o.y = f2bf(v[1]); o.z = f2bf(v[2]); o.w = f2bf(v[3]);
      *(short4*)(xbf + i) = o;
    }
    return;
  }

  if (blk < 64) {                      // ---- absorb_qk
    __shared__ float wk[32 * 64];
    const int h   = blk >> 2;
    const int dm0 = (blk & 3) * 256;
    {
      const int l  = tid >> 3;
      const int d0 = (tid & 7) * 8;
      *(f32x4*)(wk + l * 64 + d0)     = *(const f32x4*)(Wk + (size_t)l * DMODEL + h * 64 + d0);
      *(f32x4*)(wk + l * 64 + d0 + 4) = *(const f32x4*)(Wk + (size_t)l * DMODEL + h * 64 + d0 + 4);
    }
    __syncthreads();
    const int dm = dm0 + tid;
    float acc[32] = {};
    for (int dv = 0; dv < 16; ++dv) {
      const f32x4 wq = *(const f32x4*)(Wq + (size_t)dm * DMODEL + h * 64 + dv * 4);
#pragma unroll
      for (int jj = 0; jj < 4; ++jj)
#pragma unroll
        for (int l = 0; l < 32; ++l)
          acc[l] += wq[jj] * wk[l * 64 + dv * 4 + jj];
    }
    const float SCALE = 0.1803368801111f;   // (1/sqrt(64)) * log2(e)
#pragma unroll
    for (int l = 0; l < 32; ++l)
      WcombT[((size_t)(h * 32 + l)) * DMODEL + dm] = f2bf(acc[l] * SCALE);
  } else if (blk < 128) {              // ---- absorb_vo
    __shared__ float wvs[32 * 64];
    const int h  = (blk - 64) >> 2;
    const int n0 = ((blk - 64) & 3) * 256;
    {
      const int l  = tid >> 3;
      const int d0 = (tid & 7) * 8;
      *(f32x4*)(wvs + l * 64 + d0)     = *(const f32x4*)(Wv + (size_t)l * DMODEL + h * 64 + d0);
      *(f32x4*)(wvs + l * 64 + d0 + 4) = *(const f32x4*)(Wv + (size_t)l * DMODEL + h * 64 + d0 + 4);
    }
    __syncthreads();
    const int n = n0 + tid;
    float acc[32] = {};
    for (int d = 0; d < 64; ++d) {
      const float wo = Wo[(size_t)(h * 64 + d) * DMODEL + n];
#pragma unroll
      for (int l = 0; l < 32; ++l)
        acc[l] += wvs[l * 64 + d] * wo;
    }
#pragma unroll
    for (int l = 0; l < 32; ++l)
      WvoT[(size_t)n * 512 + h * 32 + l] = f2bf(acc[l]);
  } else {                             // ---- Wkv transpose + zero-fill
    const int i = (blk - 128) * 256 + tid;      // 0..32767
    const int k = i >> 5;
    const int l = i & 31;
    WcombT[(size_t)(512 + l) * DMODEL + k] = f2bf(Wkv[(size_t)k * LATENT + l]);
    // zero rows 544-639: 96*1024 = 98304 shorts = 3 per thread, exact
    short* z = WcombT + (size_t)544 * DMODEL + (size_t)i * 3;
    z[0] = 0; z[1] = 0; z[2] = 0;
  }
}

// ---------------------------------------------------------------- GEMM (big)
// m97 structure: 128x128 block tile, BK=32, 4 waves 2x2, global_load_lds w16,
// source-side XOR chunk swizzle. M%128==0, N%128==0, K%32==0.
// out_mode 3: fp32 row-major [M,N] -> Cf
// out_mode 5: cols<512 -> Qlat bf16 [M,512] (Cs); cols 512-543 -> lat bf16
//             [M,32] (Cs2) + latT [B,32,T] (Cs3); cols>=544 discarded.
__global__ __launch_bounds__(256)
void gemm128_kernel(const short* __restrict__ A, const short* __restrict__ Bt,
                    short* __restrict__ Cs, float* __restrict__ Cf,
                    short* __restrict__ Cs2, short* __restrict__ Cs3,
                    int M, int K, int N, int out_mode) {
  __shared__ short Alds[128 * 32];   // 8 KB
  __shared__ short Blds[128 * 32];   // 8 KB

  const int tid  = threadIdx.x;
  const int wv   = tid >> 6;
  const int lane = tid & 63;
  const int quad = lane >> 4;
  const int l16  = lane & 15;
  const int wm   = wv >> 1;
  const int wn   = wv & 1;

  const int nb  = N >> 7;
  const int nwg = gridDim.x;
  int bid = blockIdx.x;
  if ((nwg & 7) == 0)                // XCD swizzle (bijective: nwg%8==0)
    bid = (bid & 7) * (nwg >> 3) + (bid >> 3);
  const int mt = bid / nb;
  const int nt = bid - mt * nb;
  const int m0 = mt << 7;
  const int n0 = nt << 7;

  const int rl  = lane >> 2;
  const int cl  = lane & 3;
  const int csw = cl ^ ((rl >> 1) & 3);
  const int ra  = wv * 16 + rl;
  const short* Ag0 = A  + (size_t)(m0 + ra) * K + csw * 8;
  const short* Ag1 = A  + (size_t)(m0 + 64 + ra) * K + csw * 8;
  const short* Bg0 = Bt + (size_t)(n0 + ra) * K + csw * 8;
  const short* Bg1 = Bt + (size_t)(n0 + 64 + ra) * K + csw * 8;
  short* Al0 = &Alds[(wv * 16) * 32];
  short* Al1 = &Alds[(64 + wv * 16) * 32];
  short* Bl0 = &Blds[(wv * 16) * 32];
  short* Bl1 = &Blds[(64 + wv * 16) * 32];

  const int rsw = (l16 >> 1) & 3;
  const int coff = (quad ^ rsw) * 8;

  f32x4 acc[4][4] = {};

  for (int k0 = 0; k0 < K; k0 += 32) {
    gld_lds16(Ag0 + k0, Al0);
    gld_lds16(Ag1 + k0, Al1);
    gld_lds16(Bg0 + k0, Bl0);
    gld_lds16(Bg1 + k0, Bl1);
    __builtin_amdgcn_s_waitcnt(0x0F70);   // vmcnt(0)
    __syncthreads();

    bf16x8 af[4], bfr[4];
#pragma unroll
    for (int i = 0; i < 4; ++i) {
      const int rowA = wm * 64 + i * 16 + l16;
      const int rowB = wn * 64 + i * 16 + l16;
      af[i]  = *(const bf16x8*)&Alds[rowA * 32 + coff];
      bfr[i] = *(const bf16x8*)&Blds[rowB * 32 + coff];
    }
#pragma unroll
    for (int i = 0; i < 4; ++i)
#pragma unroll
      for (int j = 0; j < 4; ++j)
        acc[i][j] = __builtin_amdgcn_mfma_f32_16x16x32_bf16(af[i], bfr[j], acc[i][j], 0, 0, 0);
    __syncthreads();
  }

  // epilogue: C/D layout row = quad*4+r (A side), col = l16 (B side)
#pragma unroll
  for (int i = 0; i < 4; ++i) {
    const int row = m0 + wm * 64 + i * 16 + quad * 4;
#pragma unroll
    for (int j = 0; j < 4; ++j) {
      const int col = n0 + wn * 64 + j * 16 + l16;
#pragma unroll
      for (int r = 0; r < 4; ++r) {
        if (out_mode == 3) {
          Cf[(size_t)(row + r) * N + col] = acc[i][j][r];
        } else {   // mode 5
          if (col < 512) {
            Cs[(size_t)(row + r) * 512 + col] = f2bf(acc[i][j][r]);
          } else if (col < 544) {
            const short v = f2bf(acc[i][j][r]);
            const int l = col - 512;
            const int m = row + r;
            Cs2[(size_t)m * LATENT + l] = v;
            const int bb = m >> 12;            // T_SEQ = 4096
            const int tt = m & (T_SEQ - 1);
            Cs3[((size_t)(bb * LATENT + l) << 12) + tt] = v;
          }
        }
      }
    }
  }
}

// ---------------------------------------------------------------- attention
// Round-9 proven structure (best measured): latent flash attention, max-free
// softmax, TWO heads per block. Block = 4 waves = 64 queries. Per 64-key
// tile: stage lat [64x32] + latT [32x64] (8 KB, single-buffered, shared by
// both heads). Per wave per head: S^T = lat Qlat^T (4 MFMA), P = exp2(S^T),
// P roundtrip via wave-private LDS, Olat^T += latT P^T (4 MFMA),
// l += ones P^T (2 MFMA).
// Grid 1024: xcd=idx&7, head-pair=(b,hg), qb mapped so each CU's 4 striped
// blocks (jj stride 16) sum to exactly 130 tile-iters.
__global__ __launch_bounds__(256, 4)
void attn_kernel(const short* __restrict__ Qlat, short* __restrict__ Olat,
                 const short* __restrict__ latg, const short* __restrict__ latTg) {
  __shared__ short Klds[64 * 32];        // lat  [key][lat chunk swz]   4 KB
  __shared__ short Vlds[32 * 64];        // latT [lat][key chunk swz]   4 KB
  __shared__ short Plds[4][2][16 * 72];  // per-wave P, 2 heads         18 KB

  const int tid  = threadIdx.x;
  const int wv   = tid >> 6;
  const int lane = tid & 63;
  const int quad = lane >> 4;
  const int l16  = lane & 15;

  const int idx = blockIdx.x;             // 1024 blocks
  const int xcd = idx & 7;
  const int j   = idx >> 3;               // 0..127
  const int bhg = xcd * 2 + (j & 1);      // 0..15: (batch, head-pair)
  const int jj  = j >> 1;                 // 0..63
  // balanced qb: stripe groups {63-r, r, 47-r, 16+r} sum to 126 (+4 = 130 iters)
  const int a   = jj >> 4;
  const int r_  = jj & 15;
  const int qb  = (a & 1) ? ((a == 1 ? 0 : 16) + r_) : ((a == 0 ? 63 : 47) - r_);
  const int b   = bhg >> 3;
  const int hg  = bhg & 7;                // heads hg*2, hg*2+1

  const int q0 = qb * 64;
  const int qw = q0 + wv * 16;            // this wave's query base
  const int q  = qw + l16;                // this lane's query (column)

  // staging geometry (per wave, 1 instr per tile), source-side XOR swizzle
  const int srK = wv * 16 + (lane >> 2);           // lat tile row (0..63)
  const int scK = (lane & 3) ^ ((srK >> 1) & 3);   // chunk of 16B in 64B row
  const short* Ksrc = latg + ((size_t)b * T_SEQ + srK) * LATENT + scK * 8;
  const int srV = wv * 8 + (lane >> 3);            // latT tile row (0..31)
  const int scV = (lane & 7) ^ (srV & 7);          // chunk of 16B in 128B row
  const short* Vsrc = latTg + ((size_t)b * LATENT + srV) * T_SEQ + scV * 8;

  // Qlat B-fragments for both heads (cols hg*64 .. hg*64+63)
  const short* Qrow = Qlat + ((size_t)(b * T_SEQ) + qw + l16) * 512 + hg * 64;
  const bf16x8 qfA = *(const bf16x8*)(Qrow + quad * 8);
  const bf16x8 qfB = *(const bf16x8*)(Qrow + 32 + quad * 8);

  // all-ones A-fragment: row-sum of P via the matrix pipe
  bf16x8 ones;
#pragma unroll
  for (int i = 0; i < 8; ++i) ones[i] = (short)0x3F80;   // bf16 1.0

  f32x4 oA[2] = {}, oB[2] = {};
  f32x4 laccA = {}, laccB = {};
  short* PA = &Plds[wv][0][0];
  short* PB = &Plds[wv][1][0];

  auto kv_step = [&](const int k0, const bool diag) {
    gld_lds16(Ksrc + (size_t)k0 * LATENT, &Klds[(wv * 16) * 32]);
    gld_lds16(Vsrc + k0,                  &Vlds[(wv * 8) * 64]);
    __builtin_amdgcn_s_waitcnt(0x0F70);   // vmcnt(0)
    __syncthreads();

    // ---- S^T = lat Qlat^T for BOTH heads (shared K A-frag)
    f32x4 sa[4], sb[4];
    __builtin_amdgcn_s_setprio(1);
#pragma unroll
    for (int mt = 0; mt < 4; ++mt) {
      if (diag && mt > wv) {               // keys entirely above all queries
        sa[mt][0] = sa[mt][1] = sa[mt][2] = sa[mt][3] = -1e9f;
        sb[mt] = sa[mt];
        continue;
      }
      const int R = mt * 16 + l16;
      const bf16x8 kf = *(const bf16x8*)&Klds[R * 32 + ((quad ^ ((R >> 1) & 3))) * 8];
      f32x4 z = {};
      sa[mt] = __builtin_amdgcn_mfma_f32_16x16x32_bf16(kf, qfA, z, 0, 0, 0);
      sb[mt] = __builtin_amdgcn_mfma_f32_16x16x32_bf16(kf, qfB, z, 0, 0, 0);
    }
    __builtin_amdgcn_s_setprio(0);

    // ---- causal mask: only the diagonal block needs it
    if (diag) {
#pragma unroll
      for (int mt = 0; mt < 4; ++mt)
#pragma unroll
        for (int r = 0; r < 4; ++r) {
          const int key = k0 + mt * 16 + quad * 4 + r;
          if (key > q) { sa[mt][r] = -1e9f; sb[mt][r] = -1e9f; }
        }
    }

    // ---- P = exp2(S): max-free
#pragma unroll
    for (int mt = 0; mt < 4; ++mt)
#pragma unroll
      for (int r = 0; r < 4; ++r) {
        sa[mt][r] = exp2_hw(sa[mt][r]);
        sb[mt][r] = exp2_hw(sb[mt][r]);
      }

    // ---- P -> wave-private LDS (both heads), read back as B-frags
    asm volatile("" ::: "memory");
#pragma unroll
    for (int mt = 0; mt < 4; ++mt) {
      short4 wA, wB;
      wA.x = f2bf(sa[mt][0]); wA.y = f2bf(sa[mt][1]);
      wA.z = f2bf(sa[mt][2]); wA.w = f2bf(sa[mt][3]);
      *(short4*)(PA + l16 * 72 + mt * 16 + quad * 4) = wA;
      wB.x = f2bf(sb[mt][0]); wB.y = f2bf(sb[mt][1]);
      wB.z = f2bf(sb[mt][2]); wB.w = f2bf(sb[mt][3]);
      *(short4*)(PB + l16 * 72 + mt * 16 + quad * 4) = wB;
    }
    asm volatile("" ::: "memory");
    __builtin_amdgcn_s_waitcnt(0xC07F);   // lgkmcnt(0)
    asm volatile("" ::: "memory");
    const bf16x8 pfA0 = *(const bf16x8*)(PA + l16 * 72 + quad * 8);
    const bf16x8 pfA1 = *(const bf16x8*)(PA + l16 * 72 + 32 + quad * 8);
    const bf16x8 pfB0 = *(const bf16x8*)(PB + l16 * 72 + quad * 8);
    const bf16x8 pfB1 = *(const bf16x8*)(PB + l16 * 72 + 32 + quad * 8);
    asm volatile("" ::: "memory");

    // ---- Olat^T += latT P^T; l += ones P^T (both heads, shared V A-frags)
    __builtin_amdgcn_s_setprio(1);
#pragma unroll
    for (int f = 0; f < 2; ++f) {
      const int R = f * 16 + l16;
      const bf16x8 vf0 = *(const bf16x8*)&Vlds[R * 64 + ((quad    ) ^ (R & 7)) * 8];
      const bf16x8 vf1 = *(const bf16x8*)&Vlds[R * 64 + ((quad + 4) ^ (R & 7)) * 8];
      oA[f] = __builtin_amdgcn_mfma_f32_16x16x32_bf16(vf0, pfA0, oA[f], 0, 0, 0);
      oA[f] = __builtin_amdgcn_mfma_f32_16x16x32_bf16(vf1, pfA1, oA[f], 0, 0, 0);
      oB[f] = __builtin_amdgcn_mfma_f32_16x16x32_bf16(vf0, pfB0, oB[f], 0, 0, 0);
      oB[f] = __builtin_amdgcn_mfma_f32_16x16x32_bf16(vf1, pfB1, oB[f], 0, 0, 0);
    }
    laccA = __builtin_amdgcn_mfma_f32_16x16x32_bf16(ones, pfA0, laccA, 0, 0, 0);
    laccA = __builtin_amdgcn_mfma_f32_16x16x32_bf16(ones, pfA1, laccA, 0, 0, 0);
    laccB = __builtin_amdgcn_mfma_f32_16x16x32_bf16(ones, pfB0, laccB, 0, 0, 0);
    laccB = __builtin_amdgcn_mfma_f32_16x16x32_bf16(ones, pfB1, laccB, 0, 0, 0);
    __builtin_amdgcn_s_setprio(0);
    __syncthreads();   // all waves done reading Klds/Vlds before restage
  };

#pragma unroll 1
  for (int k0 = 0; k0 < q0; k0 += 64) kv_step(k0, false);   // interior
  kv_step(q0, true);                                        // diagonal

  // ---- epilogue: Olat^T C-layout row = latent = f*16+quad*4+r, col = l16.
  const float invA = 1.0f / laccA[0];
  const float invB = 1.0f / laccB[0];
  short* Orow = Olat + ((size_t)(b * T_SEQ) + qw + l16) * 512 + hg * 64;
#pragma unroll
  for (int f = 0; f < 2; ++f) {
    short4 wA, wB;
    wA.x = f2bf(oA[f][0] * invA); wA.y = f2bf(oA[f][1] * invA);
    wA.z = f2bf(oA[f][2] * invA); wA.w = f2bf(oA[f][3] * invA);
    *(short4*)(Orow + f * 16 + quad * 4) = wA;
    wB.x = f2bf(oB[f][0] * invB); wB.y = f2bf(oB[f][1] * invB);
    wB.z = f2bf(oB[f][2] * invB); wB.w = f2bf(oB[f][3] * invB);
    *(short4*)(Orow + 32 + f * 16 + quad * 4) = wB;
  }
}

// ---------------------------------------------------------------- launch
extern "C" void kernel_launch(void* const* d_in, const int* in_sizes, int n_in,
                              void* d_out, int out_size, void* d_ws, size_t ws_size,
                              hipStream_t stream) {
  const float* x   = (const float*)d_in[0];   // [2,4096,1024]
  const float* Wkv = (const float*)d_in[1];   // [1024,32]
  const float* Wk  = (const float*)d_in[2];   // [32,1024]
  const float* Wv  = (const float*)d_in[3];   // [32,1024]
  const float* Wq  = (const float*)d_in[4];   // [1024,1024]
  const float* Wo  = (const float*)d_in[5];   // [1024,1024]

  char* p = (char*)d_ws;
  auto carve = [&](size_t n) {
    char* r = p;
    p += (n + 255) & ~(size_t)255;
    return r;
  };
  short* xbf    = (short*)carve((size_t)M_ROWS * DMODEL * 2);   // 16 MB
  short* Qlat   = (short*)carve((size_t)M_ROWS * 512 * 2);      //  8 MB
  short* Olat   = (short*)carve((size_t)M_ROWS * 512 * 2);      //  8 MB
  short* lat    = (short*)carve((size_t)M_ROWS * LATENT * 2);   // 512 KB
  short* latT   = (short*)carve((size_t)M_ROWS * LATENT * 2);   // 512 KB
  short* WcombT = (short*)carve((size_t)640 * DMODEL * 2);      // 1.25 MB
  short* WvoT   = (short*)carve((size_t)DMODEL * 512 * 2);      //  1 MB

  // merged prep: weights (blocks 0-255) + x conversion (blocks 256-8447)
  prep_weights<<<256 + M_ROWS * DMODEL / 4 / 256, 256, 0, stream>>>(
      Wq, Wk, Wv, Wo, Wkv, x, WcombT, WvoT, xbf);

  // [Qlat | lat + latT] = x @ WcombT  (N=640, cols>=544 discarded)
  gemm128_kernel<<<(M_ROWS / 128) * (640 / 128), 256, 0, stream>>>(
      xbf, WcombT, Qlat, nullptr, lat, latT, M_ROWS, DMODEL, 640, 5);

  attn_kernel<<<1024, 256, 0, stream>>>(Qlat, Olat, lat, latT);

  // out = Olat @ W_vo  [M,1024] fp32
  gemm128_kernel<<<(M_ROWS / 128) * (DMODEL / 128), 256, 0, stream>>>(
      Olat, WvoT, nullptr, (float*)d_out, nullptr, nullptr, M_ROWS, 512, DMODEL, 3);
}